// Round 1
// 889.652 us; speedup vs baseline: 1.0760x; 1.0760x over previous
//
#include <hip/hip_runtime.h>
#include <hip/hip_bf16.h>

// EdgeGCNV2: h = x@Wg; GAT edge softmax + scatter; C1 = H@gat_out (bf16 MFMA);
// out = leaky(C1@We + be)@Wl.
// Sizes fixed: N_items=16384, F_in=Hd=128, Do=64, N_nodes=8192, E=524288.
// R2: counting-sort edges by dst + fused online-softmax aggregation.
// R3 (this round): k_h LDS-stages Wg (kills 1GB L2 re-read) + fuses hs/hd;
//   k_agg paired-edge inner loop (2x MLP); k_scan 1024-thread int4; k_final
//   2 blocks/CU + LDS-staged Wl. GEMM unchanged (at HBM floor).

#define NEG 0.2f
#define N_ITEMS 16384
#define N_NODES 8192
#define E_EDGES 524288
#define HD 128

typedef float f32x4 __attribute__((ext_vector_type(4)));
typedef short bf16x8 __attribute__((ext_vector_type(8)));
typedef int i32x4 __attribute__((ext_vector_type(4)));

__device__ __forceinline__ float leaky(float v) { return v >= 0.0f ? v : NEG * v; }

__device__ __forceinline__ unsigned short f2bf(float f) {  // RNE fp32->bf16
  unsigned int u = __float_as_uint(f);
  u += 0x7FFFu + ((u >> 16) & 1u);
  return (unsigned short)(u >> 16);
}

// ---------------- zero a range of float4s ----------------
__global__ __launch_bounds__(256) void k_zero(f32x4* p, int n4) {
  int i = blockIdx.x * 256 + threadIdx.x;
  int stride = gridDim.x * 256;
  f32x4 z = {0.0f, 0.0f, 0.0f, 0.0f};
  for (; i < n4; i += stride) p[i] = z;
}

// ---------------- h = x @ W_gat with LDS-staged Wg; fused hs/hd ------------
// 512 blocks x 256 threads; 32 rows/block; thread = 1 row x 16 cols.
// Wg (64KB) staged once per block -> LDS (exactly the 64KB static limit,
// 2 blocks/CU). hs = h@a_src, hd = h@a_dst reduced across the 8 lanes of a
// row via shfl_xor (lanes of a row are consecutive, stay within a wave).
__global__ __launch_bounds__(256) void k_h(const float* __restrict__ x,
                                           const float* __restrict__ Wg,
                                           const float* __restrict__ a_src,
                                           const float* __restrict__ a_dst,
                                           float* __restrict__ h,
                                           float* __restrict__ hs,
                                           float* __restrict__ hd) {
  __shared__ float Wgs[128 * 128];  // 64 KB
  const int t = threadIdx.x;
#pragma unroll
  for (int i = 0; i < 16; i++) {
    int idx = (i * 256 + t) * 4;
    *(f32x4*)&Wgs[idx] = *(const f32x4*)&Wg[idx];
  }
  __syncthreads();

  const int r = blockIdx.x * 32 + (t >> 3);
  const int cg = (t & 7) * 16;
  const float* xr = x + (size_t)r * 128;
  f32x4 acc[4] = {{0,0,0,0},{0,0,0,0},{0,0,0,0},{0,0,0,0}};
  for (int k = 0; k < 128; k++) {
    float xv = xr[k];
    const f32x4* wr = (const f32x4*)&Wgs[k * 128 + cg];
    acc[0] += xv * wr[0];
    acc[1] += xv * wr[1];
    acc[2] += xv * wr[2];
    acc[3] += xv * wr[3];
  }
  float* hrow = h + (size_t)r * 128 + cg;
  *(f32x4*)(hrow)      = acc[0];
  *(f32x4*)(hrow + 4)  = acc[1];
  *(f32x4*)(hrow + 8)  = acc[2];
  *(f32x4*)(hrow + 12) = acc[3];

  // fused hs/hd: partial dot over this thread's 16 cols, reduce over 8 lanes
  float s = 0.0f, d = 0.0f;
#pragma unroll
  for (int j = 0; j < 16; j++) {
    float hv = acc[j >> 2][j & 3];
    s += hv * a_src[cg + j];
    d += hv * a_dst[cg + j];
  }
  s += __shfl_xor(s, 1); d += __shfl_xor(d, 1);
  s += __shfl_xor(s, 2); d += __shfl_xor(d, 2);
  s += __shfl_xor(s, 4); d += __shfl_xor(d, 4);
  if ((t & 7) == 0) { hs[r] = s; hd[r] = d; }
}

// ---------------- histogram of dst ----------------
__global__ __launch_bounds__(256) void k_hist(const int* __restrict__ ei,
                                              int* __restrict__ cnt) {
  int e = blockIdx.x * 256 + threadIdx.x;
  if (e < E_EDGES) atomicAdd(&cnt[ei[E_EDGES + e]], 1);
}

// ---------------- exclusive scan of cnt[16384] -> off[16385], cur=off ------
// 1024 threads, 16 elems each (int4 loads): shorter serial runs than 256x64.
__global__ __launch_bounds__(1024) void k_scan(const int* __restrict__ cnt,
                                               int* __restrict__ off,
                                               int* __restrict__ cur) {
  __shared__ int part[1024];
  const int t = threadIdx.x;
  const int base = t * 16;
  i32x4 c[4];
#pragma unroll
  for (int i = 0; i < 4; i++) c[i] = *(const i32x4*)&cnt[base + i * 4];
  int sum = 0;
#pragma unroll
  for (int i = 0; i < 4; i++) sum += c[i][0] + c[i][1] + c[i][2] + c[i][3];
  part[t] = sum;
  __syncthreads();
  for (int o = 1; o < 1024; o <<= 1) {
    int v = (t >= o) ? part[t - o] : 0;
    __syncthreads();
    part[t] += v;
    __syncthreads();
  }
  int run = (t > 0) ? part[t - 1] : 0;
#pragma unroll
  for (int i = 0; i < 4; i++)
#pragma unroll
    for (int j = 0; j < 4; j++) {
      int idx = base + i * 4 + j;
      off[idx] = run;
      cur[idx] = run;
      run += c[i][j];
    }
  if (t == 1023) off[16384] = run;
}

// ---------------- scatter srcs into dst-sorted order ----------------
__global__ __launch_bounds__(256) void k_reorder(const int* __restrict__ ei,
                                                 int* __restrict__ cur,
                                                 int* __restrict__ es) {
  int e = blockIdx.x * 256 + threadIdx.x;
  if (e >= E_EDGES) return;
  int d = ei[E_EDGES + e];
  int pos = atomicAdd(&cur[d], 1);
  es[pos] = ei[e];
}

// ---------------- fused online-softmax aggregation: wave per dst ----------
// gat[d] = (sum_e w_e * h[src_e] + w_self * h[d]) / l  + b_gat.
// R3: paired-edge inner loop — lanes >= n carry w=0,s=0 so the odd tail is
// numerically free; both rows' loads issue before the FMA chain (2x MLP).
__global__ __launch_bounds__(256) void k_agg(const int* __restrict__ es,
                                             const int* __restrict__ off,
                                             const float* __restrict__ hs,
                                             const float* __restrict__ hd,
                                             const float* __restrict__ h,
                                             const float* __restrict__ b_gat,
                                             float* __restrict__ gat) {
  int d = blockIdx.x * 4 + (threadIdx.x >> 6);   // 4096 blocks
  int lane = threadIdx.x & 63;
  int beg = off[d], end = off[d + 1];
  float hdd = hd[d];
  // self-loop init
  float m = leaky(hs[d] + hdd);
  float l = 1.0f;
  float acc0 = h[(size_t)d * 128 + lane];
  float acc1 = h[(size_t)d * 128 + 64 + lane];

  for (int j0 = beg; j0 < end; j0 += 64) {
    int n = end - j0; if (n > 64) n = 64;
    int s = (lane < n) ? es[j0 + lane] : 0;
    float a = (lane < n) ? leaky(hs[s] + hdd) : -3.0e38f;
    // chunk max
    float cm = a;
    for (int o = 32; o; o >>= 1) cm = fmaxf(cm, __shfl_down(cm, o));
    cm = __shfl(cm, 0);
    float nm = fmaxf(m, cm);
    float scale = __expf(m - nm);
    acc0 *= scale; acc1 *= scale; l *= scale;
    m = nm;
    float w = (lane < n) ? __expf(a - nm) : 0.0f;
    float wsum = w;
    for (int o = 32; o; o >>= 1) wsum += __shfl_down(wsum, o);
    l += __shfl(wsum, 0);
    int nn = (n + 1) & ~1;
    for (int j = 0; j < nn; j += 2) {
      float w0 = __shfl(w, j);     int s0 = __shfl(s, j);
      float w1 = __shfl(w, j + 1); int s1 = __shfl(s, j + 1);
      const float* h0 = h + (size_t)s0 * 128;
      const float* h1 = h + (size_t)s1 * 128;
      float a00 = h0[lane], a01 = h0[64 + lane];
      float a10 = h1[lane], a11 = h1[64 + lane];
      acc0 = fmaf(w0, a00, acc0);
      acc1 = fmaf(w0, a01, acc1);
      acc0 = fmaf(w1, a10, acc0);
      acc1 = fmaf(w1, a11, acc1);
    }
  }
  float inv = 1.0f / l;
  gat[(size_t)d * 128 + lane]      = acc0 * inv + b_gat[lane];
  gat[(size_t)d * 128 + 64 + lane] = acc1 * inv + b_gat[64 + lane];
}

// ---------------- gat (fp32, bias included) -> bf16 transposed Gt[128][16384] ----
__global__ __launch_bounds__(256) void k_cvt(const float* __restrict__ gat,
                                             unsigned short* __restrict__ Gt) {
  __shared__ unsigned short T[128][65];
  int r0 = blockIdx.x * 64;
  int t = threadIdx.x;
#pragma unroll
  for (int i = 0; i < 32; i++) {
    int flat = i * 256 + t;
    int r = flat >> 7, c = flat & 127;
    T[c][r] = f2bf(gat[(size_t)(r0 + r) * 128 + c]);
  }
  __syncthreads();
#pragma unroll
  for (int i = 0; i < 32; i++) {
    int flat = i * 256 + t;
    int c = flat >> 6, r = flat & 63;
    Gt[(size_t)c * 16384 + r0 + r] = T[c][r];
  }
}

// ---------------- C1 = H @ gat_out  (bf16 MFMA, BM=32, BK=64, splitK=4) ----------------
#define GB_LDA 72
#define GB_LDB 72

__device__ __forceinline__ f32x4 mfma16(bf16x8 a, bf16x8 b, f32x4 c) {
  return __builtin_amdgcn_mfma_f32_16x16x32_bf16(a, b, c, 0, 0, 0);
}

__global__ __launch_bounds__(256, 4) void k_gemm_big(const float* __restrict__ Hm,
                                                     const unsigned short* __restrict__ Gt,
                                                     float* __restrict__ C1) {
  __shared__ __align__(16) unsigned short As[32 * GB_LDA];
  __shared__ __align__(16) unsigned short Bs[128 * GB_LDB];

  // XCD swizzle: ksplit constant per XCD (bid%8 & 3), so each XCD's L2 keeps one 1MB B-slice
  const int g = blockIdx.x & 7;
  const int ksplit = g & 3;
  const int mt = ((blockIdx.x >> 3) << 1) | (g >> 2);   // 0..255
  const int m0 = mt * 32;
  const int kbeg = ksplit * 4096;

  const int t = threadIdx.x;
  const int lane = t & 63;
  const int wave = t >> 6;
  const int wm = wave & 1;   // M slice (16 rows)
  const int wn = wave >> 1;  // N half (64 cols)

  f32x4 acc0 = {0,0,0,0}, acc1 = {0,0,0,0}, acc2 = {0,0,0,0}, acc3 = {0,0,0,0};

  const int ar = t >> 3;
  const int ac = (t & 7) * 8;
  const float* Ap = Hm + (size_t)(m0 + ar) * 16384 + ac + kbeg;
  unsigned short* AsW = &As[ar * GB_LDA + ac];

  const int bc = t >> 1;
  const int bsg = (t & 1) * 32;
  const unsigned short* Bp = Gt + (size_t)bc * 16384 + bsg + kbeg;
  unsigned short* BsW = &Bs[bc * GB_LDB + bsg];

  const unsigned short* AsR = &As[(wm * 16 + (lane & 15)) * GB_LDA + (lane >> 4) * 8];
  const unsigned short* BsR = &Bs[(wn * 64 + (lane & 15)) * GB_LDB + (lane >> 4) * 8];

  for (int k0 = 0; k0 < 4096; k0 += 64) {
    f32x4 a0 = *(const f32x4*)(Ap + k0);
    f32x4 a1 = *(const f32x4*)(Ap + k0 + 4);
    bf16x8 b0 = *(const bf16x8*)(Bp + k0);
    bf16x8 b1 = *(const bf16x8*)(Bp + k0 + 8);
    bf16x8 b2 = *(const bf16x8*)(Bp + k0 + 16);
    bf16x8 b3 = *(const bf16x8*)(Bp + k0 + 24);
    bf16x8 av;
    av[0] = (short)f2bf(a0[0]); av[1] = (short)f2bf(a0[1]);
    av[2] = (short)f2bf(a0[2]); av[3] = (short)f2bf(a0[3]);
    av[4] = (short)f2bf(a1[0]); av[5] = (short)f2bf(a1[1]);
    av[6] = (short)f2bf(a1[2]); av[7] = (short)f2bf(a1[3]);

    __syncthreads();
    *(bf16x8*)AsW = av;
    *(bf16x8*)(BsW)      = b0;
    *(bf16x8*)(BsW + 8)  = b1;
    *(bf16x8*)(BsW + 16) = b2;
    *(bf16x8*)(BsW + 24) = b3;
    __syncthreads();

#pragma unroll
    for (int kk = 0; kk < 2; kk++) {
      bf16x8 af = *(const bf16x8*)(AsR + kk * 32);
      acc0 = mfma16(af, *(const bf16x8*)(BsR + kk * 32), acc0);
      acc1 = mfma16(af, *(const bf16x8*)(BsR + 16 * GB_LDB + kk * 32), acc1);
      acc2 = mfma16(af, *(const bf16x8*)(BsR + 32 * GB_LDB + kk * 32), acc2);
      acc3 = mfma16(af, *(const bf16x8*)(BsR + 48 * GB_LDB + kk * 32), acc3);
    }
  }

  // epilogue: C/D layout col=lane&15, row=(lane>>4)*4+reg  -> atomicAdd (split-K)
  const int erow = m0 + wm * 16 + ((lane >> 4) << 2);
  const int ecol = wn * 64 + (lane & 15);
  f32x4 accs[4] = {acc0, acc1, acc2, acc3};
#pragma unroll
  for (int nt = 0; nt < 4; nt++)
#pragma unroll
    for (int r = 0; r < 4; r++)
      atomicAdd(&C1[(size_t)(erow + r) * 128 + ecol + nt * 16], accs[nt][r]);
}

// ---------------- out = leaky(C1@We + be) @ Wl ----------------
// R3: 512 blocks x 16 rows (2 blocks/CU), Wl staged in 32KB LDS.
__global__ __launch_bounds__(256) void k_final(const float* __restrict__ C1,
                                               const float* __restrict__ We,
                                               const float* __restrict__ be,
                                               const float* __restrict__ Wl,
                                               float* __restrict__ out) {
  __shared__ float t1[16][132];
  __shared__ float Wls[8192];   // 32 KB
  const int t = threadIdx.x;
#pragma unroll
  for (int i = 0; i < 8; i++) {
    int idx = (i * 256 + t) * 4;
    *(f32x4*)&Wls[idx] = *(const f32x4*)&Wl[idx];
  }
  const int r0 = blockIdx.x * 16;
  const int r = t >> 4;
  const int cg = (t & 15) * 8;
  const float* cr = C1 + (size_t)(r0 + r) * 128;
  f32x4 acc[2] = {{0,0,0,0},{0,0,0,0}};
  for (int k = 0; k < 128; k++) {
    float cv = cr[k];
    const f32x4* wrow = (const f32x4*)&We[k * 128 + cg];
    acc[0] += cv * wrow[0];
    acc[1] += cv * wrow[1];
  }
#pragma unroll
  for (int j = 0; j < 8; j++) {
    float v = acc[j >> 2][j & 3] + be[cg + j];
    t1[r][cg + j] = leaky(v);
  }
  __syncthreads();
  const int c4 = (t & 15) * 4;
  f32x4 acc2 = {0,0,0,0};
  for (int k = 0; k < 128; k++) {
    float tv = t1[r][k];
    acc2 += tv * *(const f32x4*)&Wls[k * 64 + c4];
  }
  *(f32x4*)&out[(size_t)(r0 + r) * 64 + c4] = acc2;
}

// ---------------- launch ----------------
extern "C" void kernel_launch(void* const* d_in, const int* in_sizes, int n_in,
                              void* d_out, int out_size, void* d_ws, size_t ws_size,
                              hipStream_t stream) {
  const float* x      = (const float*)d_in[0];
  const float* Hm     = (const float*)d_in[1];
  const int*   ei     = (const int*)d_in[2];     // int32 in harness (NOT int64)
  const float* Wg     = (const float*)d_in[3];
  const float* a_src  = (const float*)d_in[4];
  const float* a_dst  = (const float*)d_in[5];
  const float* b_gat  = (const float*)d_in[6];
  const float* We     = (const float*)d_in[7];
  const float* be     = (const float*)d_in[8];
  const float* Wl     = (const float*)d_in[9];
  float* out = (float*)d_out;

  // ws layout (~19.3 MB):
  //   [0       , 8M )  h [16384,128] f32      -> reused as Gt bf16 [128,16384] (4 MB)
  //   [8M      , 16M)  gat [16384,128] f32    -> reused as C1 [8192,128] f32 (4 MB)
  //   [16M     , +64K) hs
  //   [+64K    , +64K) hd
  //   [+128K   , +64K) cnt
  //   [+192K   ,+128K) off (16385 ints)
  //   [+320K   , +64K) cur
  //   [+384K   , +2M ) es (sorted srcs)
  char* ws = (char*)d_ws;
  float*          h     = (float*)(ws);
  float*          gat   = (float*)(ws + 8388608);
  float*          hs    = (float*)(ws + 16777216);
  float*          hd    = (float*)(ws + 16842752);
  int*            cnt   = (int*)  (ws + 16908288);
  int*            off   = (int*)  (ws + 16973824);
  int*            cur   = (int*)  (ws + 17104896);
  int*            es    = (int*)  (ws + 17170432);
  unsigned short* Gt    = (unsigned short*)ws;        // aliases h (dead after k_agg)
  float*          C1    = (float*)(ws + 8388608);     // aliases gat (dead after k_cvt)

  k_zero<<<64, 256, 0, stream>>>((f32x4*)cnt, 4096);  // zero cnt (64 KB)
  k_h<<<512, 256, 0, stream>>>(x, Wg, a_src, a_dst, h, hs, hd);
  k_hist<<<E_EDGES / 256, 256, 0, stream>>>(ei, cnt);
  k_scan<<<1, 1024, 0, stream>>>(cnt, off, cur);
  k_reorder<<<E_EDGES / 256, 256, 0, stream>>>(ei, cur, es);
  k_agg<<<4096, 256, 0, stream>>>(es, off, hs, hd, h, b_gat, gat);
  k_cvt<<<256, 256, 0, stream>>>(gat, Gt);            // h region overwritten by Gt here
  k_zero<<<1024, 256, 0, stream>>>((f32x4*)C1, 262144);  // zero C1 (4 MB)
  k_gemm_big<<<1024, 256, 0, stream>>>(Hm, Gt, C1);
  k_final<<<512, 256, 0, stream>>>(C1, We, be, Wl, out);
}